// Round 1
// baseline (274.963 us; speedup 1.0000x reference)
//
#include <hip/hip_runtime.h>
#include <cstdint>
#include <cstddef>

#define B_ 16
#define T_ 8192
#define D_ 256
#define U_ 256

// ---------------- Kernel 1: hidden = query @ W2  -> [B, U] ----------------
__global__ __launch_bounds__(256) void hidden_kernel(const float* __restrict__ q,
                                                     const float* __restrict__ W2,
                                                     float* __restrict__ hidden) {
    const int b = blockIdx.x;
    const int u = threadIdx.x;
    __shared__ float qs[D_];
    qs[u] = q[b * D_ + u];
    __syncthreads();
    float acc = 0.f;
#pragma unroll 8
    for (int d = 0; d < D_; ++d)
        acc += qs[d] * W2[d * U_ + u];
    hidden[b * U_ + u] = acc;
}

// ---------------- Kernel 2: scores[b][t] = V^T tanh(value_t @ W1 + hidden_b) ----
// Tile: 64 t-rows x 256 u-cols, K=256 in chunks of 32.
// 256 threads as (tt 0..15) x (uu 0..15); micro-tile 4 rows x 16 cols.
// Thread's cols: u = c*64 + uu*4 + j  (c 0..3, j 0..3)  -> 4x float4 LDS reads.
#define TB 64
#define DC 32

__global__ __launch_bounds__(256) void scores_kernel(const float* __restrict__ value,
                                                     const float* __restrict__ W1,
                                                     const float* __restrict__ Vv,
                                                     const float* __restrict__ hidden,
                                                     float* __restrict__ scores) {
    const int b   = blockIdx.y;
    const int t0  = blockIdx.x * TB;
    const int tid = threadIdx.x;
    const int uu  = tid & 15;
    const int tt  = tid >> 4;

    __shared__ float Al[DC][TB];   // [k][t]
    __shared__ float Bl[DC][U_];   // [k][u]

    float acc[4][16];
#pragma unroll
    for (int r = 0; r < 4; ++r)
#pragma unroll
        for (int c = 0; c < 16; ++c) acc[r][c] = 0.f;

    const float* vbase = value + ((size_t)b * T_ + t0) * D_;

    for (int d0 = 0; d0 < D_; d0 += DC) {
        __syncthreads();
        // stage A: value rows t0..t0+63, cols d0..d0+31 -> Al[k][t] (transposed)
#pragma unroll
        for (int rep = 0; rep < 2; ++rep) {
            const int idx = tid + rep * 256;     // float4 index 0..511
            const int t  = idx >> 3;             // 0..63
            const int c4 = idx & 7;              // 0..7
            const float4 v4 = *reinterpret_cast<const float4*>(vbase + (size_t)t * D_ + d0 + c4 * 4);
            Al[c4 * 4 + 0][t] = v4.x;
            Al[c4 * 4 + 1][t] = v4.y;
            Al[c4 * 4 + 2][t] = v4.z;
            Al[c4 * 4 + 3][t] = v4.w;
        }
        // stage B: W1 rows d0..d0+31 (each 256 floats) -> Bl[k][u] (straight copy)
        {
            const float* wbase = W1 + (size_t)d0 * U_;
#pragma unroll
            for (int rep = 0; rep < 8; ++rep) {
                const int idx = tid + rep * 256; // float4 index 0..2047
                *reinterpret_cast<float4*>(&Bl[idx >> 6][(idx & 63) * 4]) =
                    *reinterpret_cast<const float4*>(wbase + (size_t)idx * 4);
            }
        }
        __syncthreads();

#pragma unroll
        for (int kk = 0; kk < DC; ++kk) {
            const float4 av = *reinterpret_cast<const float4*>(&Al[kk][tt * 4]);
            float a[4] = {av.x, av.y, av.z, av.w};
            float bv[16];
#pragma unroll
            for (int c = 0; c < 4; ++c) {
                const float4 b4 = *reinterpret_cast<const float4*>(&Bl[kk][c * 64 + uu * 4]);
                bv[c * 4 + 0] = b4.x;
                bv[c * 4 + 1] = b4.y;
                bv[c * 4 + 2] = b4.z;
                bv[c * 4 + 3] = b4.w;
            }
#pragma unroll
            for (int r = 0; r < 4; ++r)
#pragma unroll
                for (int c = 0; c < 16; ++c)
                    acc[r][c] += a[r] * bv[c];
        }
    }

    // epilogue: add hidden, tanh, dot with V, reduce across uu
    float part[4] = {0.f, 0.f, 0.f, 0.f};
#pragma unroll
    for (int c = 0; c < 4; ++c) {
        const float4 hv = *reinterpret_cast<const float4*>(hidden + (size_t)b * U_ + c * 64 + uu * 4);
        const float4 vv = *reinterpret_cast<const float4*>(Vv + c * 64 + uu * 4);
        const float h[4]  = {hv.x, hv.y, hv.z, hv.w};
        const float vw[4] = {vv.x, vv.y, vv.z, vv.w};
#pragma unroll
        for (int j = 0; j < 4; ++j) {
#pragma unroll
            for (int r = 0; r < 4; ++r)
                part[r] += tanhf(acc[r][c * 4 + j] + h[j]) * vw[j];
        }
    }
#pragma unroll
    for (int m = 1; m < 16; m <<= 1) {
#pragma unroll
        for (int r = 0; r < 4; ++r)
            part[r] += __shfl_xor(part[r], m, 64);
    }
    if (uu == 0) {
#pragma unroll
        for (int r = 0; r < 4; ++r)
            scores[(size_t)b * T_ + t0 + tt * 4 + r] = part[r];
    }
}

// ---------------- Kernel 3: per-b softmax stats (max, 1/sum) ----------------
__global__ __launch_bounds__(256) void softmax_stats_kernel(const float* __restrict__ scores,
                                                            float* __restrict__ stats) {
    const int b = blockIdx.x;
    const int tid = threadIdx.x;
    const float* s = scores + (size_t)b * T_;
    float m = -1e30f;
    for (int t = tid; t < T_; t += 256) m = fmaxf(m, s[t]);
#pragma unroll
    for (int k = 1; k < 64; k <<= 1) m = fmaxf(m, __shfl_xor(m, k, 64));
    __shared__ float redm[4];
    const int wave = tid >> 6;
    if ((tid & 63) == 0) redm[wave] = m;
    __syncthreads();
    m = fmaxf(fmaxf(redm[0], redm[1]), fmaxf(redm[2], redm[3]));

    float l = 0.f;
    for (int t = tid; t < T_; t += 256) l += __expf(s[t] - m);
#pragma unroll
    for (int k = 1; k < 64; k <<= 1) l += __shfl_xor(l, k, 64);
    __shared__ float redl[4];
    if ((tid & 63) == 0) redl[wave] = l;
    __syncthreads();
    if (tid == 0) {
        l = redl[0] + redl[1] + redl[2] + redl[3];
        stats[b * 2 + 0] = m;
        stats[b * 2 + 1] = 1.f / l;
    }
}

// ---------------- Kernel 4: context partials over 256-t chunks ----------------
#define TCH 256
__global__ __launch_bounds__(256) void context_partial_kernel(const float* __restrict__ value,
                                                              const float* __restrict__ scores,
                                                              const float* __restrict__ stats,
                                                              float* __restrict__ partial) {
    const int b = blockIdx.y;
    const int chunk = blockIdx.x;   // 0..31
    const int d = threadIdx.x;
    const int t0 = chunk * TCH;
    const float m = stats[b * 2 + 0];
    const float invl = stats[b * 2 + 1];
    __shared__ float w[TCH];
    w[d] = __expf(scores[(size_t)b * T_ + t0 + d] - m) * invl;
    __syncthreads();
    const float* vb = value + ((size_t)b * T_ + t0) * D_;
    float acc = 0.f;
#pragma unroll 4
    for (int t = 0; t < TCH; ++t)
        acc += w[t] * vb[(size_t)t * D_ + d];
    partial[((size_t)b * (T_ / TCH) + chunk) * D_ + d] = acc;
}

// ---------------- Kernel 5: final reduce ----------------
__global__ __launch_bounds__(256) void context_reduce_kernel(const float* __restrict__ partial,
                                                             float* __restrict__ out) {
    const int b = blockIdx.x;
    const int d = threadIdx.x;
    float acc = 0.f;
#pragma unroll
    for (int c = 0; c < T_ / TCH; ++c)
        acc += partial[((size_t)b * (T_ / TCH) + c) * D_ + d];
    out[b * D_ + d] = acc;
}

extern "C" void kernel_launch(void* const* d_in, const int* in_sizes, int n_in,
                              void* d_out, int out_size, void* d_ws, size_t ws_size,
                              hipStream_t stream) {
    const float* q     = (const float*)d_in[0];
    const float* value = (const float*)d_in[1];
    const float* W1    = (const float*)d_in[2];
    const float* W2    = (const float*)d_in[3];
    const float* Vv    = (const float*)d_in[4];
    float* out = (float*)d_out;

    char* ws = (char*)d_ws;
    float* scores  = (float*)(ws);                                  // B*T        = 524288 B
    float* hidden  = (float*)(ws + 524288);                         // B*U        =  16384 B
    float* stats   = (float*)(ws + 524288 + 16384);                 // 2*B        =    128 B
    float* partial = (float*)(ws + 524288 + 16384 + 128);           // B*32*D     = 524288 B

    hidden_kernel<<<dim3(B_), dim3(256), 0, stream>>>(q, W2, hidden);

    dim3 g2(T_ / TB, B_);
    scores_kernel<<<g2, dim3(256), 0, stream>>>(value, W1, Vv, hidden, scores);

    softmax_stats_kernel<<<dim3(B_), dim3(256), 0, stream>>>(scores, stats);

    dim3 g4(T_ / TCH, B_);
    context_partial_kernel<<<g4, dim3(256), 0, stream>>>(value, scores, stats, partial);

    context_reduce_kernel<<<dim3(B_), dim3(256), 0, stream>>>(partial, out);
}

// Round 2
// 185.969 us; speedup vs baseline: 1.4785x; 1.4785x over previous
//
#include <hip/hip_runtime.h>
#include <cstdint>
#include <cstddef>

#define B_ 16
#define T_ 8192
#define D_ 256
#define U_ 256

typedef __attribute__((ext_vector_type(8))) short bf16x8;
typedef __attribute__((ext_vector_type(4))) float f32x4;
typedef __attribute__((ext_vector_type(4))) unsigned int u32x4;

__device__ inline f32x4 mfma16(bf16x8 a, bf16x8 b, f32x4 c) {
    return __builtin_amdgcn_mfma_f32_16x16x32_bf16(a, b, c, 0, 0, 0);
}

// pack high-16 (truncated bf16) of two fp32 into one u32: [y_hi16 : x_hi16]
__device__ inline unsigned int pack2_hi(float x, float y) {
    return __builtin_amdgcn_perm(__float_as_uint(y), __float_as_uint(x), 0x07060302u);
}
__device__ inline float lo_part(float x) {
    return x - __uint_as_float(__float_as_uint(x) & 0xffff0000u);
}

// convert 8 contiguous fp32 -> bf16 hi/lo fragments (truncation split)
__device__ inline void cvt8(const float* __restrict__ p, bf16x8& hi, bf16x8& lo) {
    const float4 a = *reinterpret_cast<const float4*>(p);
    const float4 b = *reinterpret_cast<const float4*>(p + 4);
    u32x4 h, l;
    h[0] = pack2_hi(a.x, a.y);
    h[1] = pack2_hi(a.z, a.w);
    h[2] = pack2_hi(b.x, b.y);
    h[3] = pack2_hi(b.z, b.w);
    l[0] = pack2_hi(lo_part(a.x), lo_part(a.y));
    l[1] = pack2_hi(lo_part(a.z), lo_part(a.w));
    l[2] = pack2_hi(lo_part(b.x), lo_part(b.y));
    l[3] = pack2_hi(lo_part(b.z), lo_part(b.w));
    hi = __builtin_bit_cast(bf16x8, h);
    lo = __builtin_bit_cast(bf16x8, l);
}

// ---------------- Kernel 0: W1 [d][u] -> W1^T bf16 hi/lo [u][d] ----------------
__global__ __launch_bounds__(256) void prep_w1t_kernel(const float* __restrict__ W1,
                                                       unsigned short* __restrict__ hi,
                                                       unsigned short* __restrict__ lo) {
    const int idx = blockIdx.x * 256 + threadIdx.x;   // 0..65535
    const int d = idx >> 8;
    const int u = idx & 255;
    const float x = W1[idx];
    const unsigned int xb = __float_as_uint(x);
    const unsigned short h = (unsigned short)(xb >> 16);
    const float lf = x - __uint_as_float(xb & 0xffff0000u);
    const unsigned short lo16 = (unsigned short)(__float_as_uint(lf) >> 16);
    hi[u * D_ + d] = h;
    lo[u * D_ + d] = lo16;
}

// ---------------- Kernel 1: hidden = query @ W2  -> [B, U] ----------------
__global__ __launch_bounds__(256) void hidden_kernel(const float* __restrict__ q,
                                                     const float* __restrict__ W2,
                                                     float* __restrict__ hidden) {
    const int b = blockIdx.x;
    const int u = threadIdx.x;
    __shared__ float qs[D_];
    qs[u] = q[b * D_ + u];
    __syncthreads();
    float acc = 0.f;
#pragma unroll 8
    for (int d = 0; d < D_; ++d)
        acc += qs[d] * W2[d * U_ + u];
    hidden[b * U_ + u] = acc;
}

// ---------------- Kernel 2: scores via bf16x3 split-precision MFMA ----------------
// Block: 64 t-rows x 256 u-cols, 4 waves; wave w owns u in [w*64, w*64+64).
// A frag (lane l): value[t0+tf*16+(l&15)][k0+(l>>4)*8 + 0..7]   (fp32 -> bf16 hi/lo)
// B frag (lane l): W1T[u0+uf*16+(l&15)][k0+(l>>4)*8 + 0..7]     (bf16, one 16B load)
// C      (lane l, reg r): keys[t0+tf*16+(l>>4)*4+r][u0+uf*16+(l&15)]
__global__ __launch_bounds__(256) void scores_mfma_kernel(
        const float* __restrict__ value,
        const unsigned short* __restrict__ w1t_hi,
        const unsigned short* __restrict__ w1t_lo,
        const float* __restrict__ Vv,
        const float* __restrict__ hidden,
        float* __restrict__ scores) {
    const int b    = blockIdx.y;
    const int t0   = blockIdx.x * 64;
    const int tid  = threadIdx.x;
    const int wave = tid >> 6;
    const int lane = tid & 63;
    const int lr   = lane & 15;
    const int lk   = lane >> 4;
    const int u0   = wave * 64;

    f32x4 acc[4][4] = {};

    const float* abase = value + ((size_t)b * T_ + t0 + lr) * D_ + lk * 8;
    const unsigned short* bh_base = w1t_hi + (size_t)(u0 + lr) * D_ + lk * 8;
    const unsigned short* bl_base = w1t_lo + (size_t)(u0 + lr) * D_ + lk * 8;

    for (int k0 = 0; k0 < D_; k0 += 32) {
        bf16x8 ah[4], al[4];
#pragma unroll
        for (int tf = 0; tf < 4; ++tf)
            cvt8(abase + (size_t)tf * 16 * D_ + k0, ah[tf], al[tf]);
#pragma unroll
        for (int uf = 0; uf < 4; ++uf) {
            const bf16x8 bh = *reinterpret_cast<const bf16x8*>(bh_base + (size_t)uf * 16 * D_ + k0);
            const bf16x8 bl = *reinterpret_cast<const bf16x8*>(bl_base + (size_t)uf * 16 * D_ + k0);
#pragma unroll
            for (int tf = 0; tf < 4; ++tf) {
                acc[tf][uf] = mfma16(ah[tf], bh, acc[tf][uf]);
                acc[tf][uf] = mfma16(al[tf], bh, acc[tf][uf]);
                acc[tf][uf] = mfma16(ah[tf], bl, acc[tf][uf]);
            }
        }
    }

    // epilogue: keys + hidden -> tanh -> dot V -> reduce over u
    float hv[4], vw[4];
#pragma unroll
    for (int uf = 0; uf < 4; ++uf) {
        const int u = u0 + uf * 16 + lr;
        hv[uf] = hidden[b * U_ + u];
        vw[uf] = Vv[u];
    }
    __shared__ float red[4][64];
#pragma unroll
    for (int tf = 0; tf < 4; ++tf) {
#pragma unroll
        for (int r = 0; r < 4; ++r) {
            float p = 0.f;
#pragma unroll
            for (int uf = 0; uf < 4; ++uf) {
                const float z = acc[tf][uf][r] + hv[uf];
                const float e = __expf(2.f * z);
                const float th = 1.f - __fdividef(2.f, e + 1.f);
                p += th * vw[uf];
            }
            p += __shfl_xor(p, 1, 64);
            p += __shfl_xor(p, 2, 64);
            p += __shfl_xor(p, 4, 64);
            p += __shfl_xor(p, 8, 64);
            if (lr == 0) red[wave][tf * 16 + lk * 4 + r] = p;
        }
    }
    __syncthreads();
    if (tid < 64) {
        const float s = red[0][tid] + red[1][tid] + red[2][tid] + red[3][tid];
        scores[(size_t)b * T_ + t0 + tid] = s;
    }
}

// ---------------- Kernel 3: per-b softmax stats (max, 1/sum) ----------------
__global__ __launch_bounds__(256) void softmax_stats_kernel(const float* __restrict__ scores,
                                                            float* __restrict__ stats) {
    const int b = blockIdx.x;
    const int tid = threadIdx.x;
    const float* s = scores + (size_t)b * T_;
    float m = -1e30f;
    for (int t = tid; t < T_; t += 256) m = fmaxf(m, s[t]);
#pragma unroll
    for (int k = 1; k < 64; k <<= 1) m = fmaxf(m, __shfl_xor(m, k, 64));
    __shared__ float redm[4];
    const int wave = tid >> 6;
    if ((tid & 63) == 0) redm[wave] = m;
    __syncthreads();
    m = fmaxf(fmaxf(redm[0], redm[1]), fmaxf(redm[2], redm[3]));

    float l = 0.f;
    for (int t = tid; t < T_; t += 256) l += __expf(s[t] - m);
#pragma unroll
    for (int k = 1; k < 64; k <<= 1) l += __shfl_xor(l, k, 64);
    __shared__ float redl[4];
    if ((tid & 63) == 0) redl[wave] = l;
    __syncthreads();
    if (tid == 0) {
        l = redl[0] + redl[1] + redl[2] + redl[3];
        stats[b * 2 + 0] = m;
        stats[b * 2 + 1] = 1.f / l;
    }
}

// ---------------- Kernel 4: context partials over 256-t chunks ----------------
#define TCH 256
__global__ __launch_bounds__(256) void context_partial_kernel(const float* __restrict__ value,
                                                              const float* __restrict__ scores,
                                                              const float* __restrict__ stats,
                                                              float* __restrict__ partial) {
    const int b = blockIdx.y;
    const int chunk = blockIdx.x;   // 0..31
    const int d = threadIdx.x;
    const int t0 = chunk * TCH;
    const float m = stats[b * 2 + 0];
    const float invl = stats[b * 2 + 1];
    __shared__ float w[TCH];
    w[d] = __expf(scores[(size_t)b * T_ + t0 + d] - m) * invl;
    __syncthreads();
    const float* vb = value + ((size_t)b * T_ + t0) * D_;
    float acc = 0.f;
#pragma unroll 4
    for (int t = 0; t < TCH; ++t)
        acc += w[t] * vb[(size_t)t * D_ + d];
    partial[((size_t)b * (T_ / TCH) + chunk) * D_ + d] = acc;
}

// ---------------- Kernel 5: final reduce ----------------
__global__ __launch_bounds__(256) void context_reduce_kernel(const float* __restrict__ partial,
                                                             float* __restrict__ out) {
    const int b = blockIdx.x;
    const int d = threadIdx.x;
    float acc = 0.f;
#pragma unroll
    for (int c = 0; c < T_ / TCH; ++c)
        acc += partial[((size_t)b * (T_ / TCH) + c) * D_ + d];
    out[b * D_ + d] = acc;
}

extern "C" void kernel_launch(void* const* d_in, const int* in_sizes, int n_in,
                              void* d_out, int out_size, void* d_ws, size_t ws_size,
                              hipStream_t stream) {
    const float* q     = (const float*)d_in[0];
    const float* value = (const float*)d_in[1];
    const float* W1    = (const float*)d_in[2];
    const float* W2    = (const float*)d_in[3];
    const float* Vv    = (const float*)d_in[4];
    float* out = (float*)d_out;

    char* ws = (char*)d_ws;
    float*          scores  = (float*)(ws);                                   // 524288 B
    float*          hidden  = (float*)(ws + 524288);                          //  16384 B
    float*          stats   = (float*)(ws + 524288 + 16384);                  //    128 B
    float*          partial = (float*)(ws + 524288 + 16384 + 128);            // 524288 B
    unsigned short* w1t_hi  = (unsigned short*)(ws + 524288 + 16384 + 128 + 524288);           // 131072 B
    unsigned short* w1t_lo  = (unsigned short*)(ws + 524288 + 16384 + 128 + 524288 + 131072);  // 131072 B

    prep_w1t_kernel<<<dim3(256), dim3(256), 0, stream>>>(W1, w1t_hi, w1t_lo);
    hidden_kernel<<<dim3(B_), dim3(256), 0, stream>>>(q, W2, hidden);

    dim3 g2(T_ / 64, B_);
    scores_mfma_kernel<<<g2, dim3(256), 0, stream>>>(value, w1t_hi, w1t_lo, Vv, hidden, scores);

    softmax_stats_kernel<<<dim3(B_), dim3(256), 0, stream>>>(scores, stats);

    dim3 g4(T_ / TCH, B_);
    context_partial_kernel<<<g4, dim3(256), 0, stream>>>(value, scores, stats, partial);

    context_reduce_kernel<<<dim3(B_), dim3(256), 0, stream>>>(partial, out);
}

// Round 3
// 102.945 us; speedup vs baseline: 2.6710x; 1.8065x over previous
//
#include <hip/hip_runtime.h>
#include <cstdint>
#include <cstddef>

#define B_ 16
#define T_ 8192
#define D_ 256
#define U_ 256

typedef __attribute__((ext_vector_type(8))) short bf16x8;
typedef __attribute__((ext_vector_type(4))) float f32x4;
typedef __attribute__((ext_vector_type(4))) unsigned int u32x4;

__device__ inline f32x4 mfma16(bf16x8 a, bf16x8 b, f32x4 c) {
    return __builtin_amdgcn_mfma_f32_16x16x32_bf16(a, b, c, 0, 0, 0);
}

// pack high-16 (truncated bf16) of two fp32 into one u32: [y_hi16 : x_hi16]
__device__ inline unsigned int pack2_hi(float x, float y) {
    return __builtin_amdgcn_perm(__float_as_uint(y), __float_as_uint(x), 0x07060302u);
}
__device__ inline float lo_part(float x) {
    return x - __uint_as_float(__float_as_uint(x) & 0xffff0000u);
}

// convert 8 contiguous fp32 -> bf16 hi/lo fragments (truncation split)
__device__ inline void cvt8(const float* __restrict__ p, bf16x8& hi, bf16x8& lo) {
    const float4 a = *reinterpret_cast<const float4*>(p);
    const float4 b = *reinterpret_cast<const float4*>(p + 4);
    u32x4 h, l;
    h[0] = pack2_hi(a.x, a.y);
    h[1] = pack2_hi(a.z, a.w);
    h[2] = pack2_hi(b.x, b.y);
    h[3] = pack2_hi(b.z, b.w);
    l[0] = pack2_hi(lo_part(a.x), lo_part(a.y));
    l[1] = pack2_hi(lo_part(a.z), lo_part(a.w));
    l[2] = pack2_hi(lo_part(b.x), lo_part(b.y));
    l[3] = pack2_hi(lo_part(b.z), lo_part(b.w));
    hi = __builtin_bit_cast(bf16x8, h);
    lo = __builtin_bit_cast(bf16x8, l);
}

// ---------------- Kernel 0: W1 [d][u] -> W1^T bf16 hi/lo [u][d] ----------------
__global__ __launch_bounds__(256) void prep_w1t_kernel(const float* __restrict__ W1,
                                                       unsigned short* __restrict__ hi,
                                                       unsigned short* __restrict__ lo) {
    const int idx = blockIdx.x * 256 + threadIdx.x;   // 0..65535
    const int d = idx >> 8;
    const int u = idx & 255;
    const float x = W1[idx];
    const unsigned int xb = __float_as_uint(x);
    const unsigned short h = (unsigned short)(xb >> 16);
    const float lf = x - __uint_as_float(xb & 0xffff0000u);
    const unsigned short lo16 = (unsigned short)(__float_as_uint(lf) >> 16);
    hi[u * D_ + d] = h;
    lo[u * D_ + d] = lo16;
}

// ---------------- Kernel 1: hidden = query @ W2  -> [B, U] ----------------
__global__ __launch_bounds__(256) void hidden_kernel(const float* __restrict__ q,
                                                     const float* __restrict__ W2,
                                                     float* __restrict__ hidden) {
    const int b = blockIdx.x;
    const int u = threadIdx.x;
    __shared__ float qs[D_];
    qs[u] = q[b * D_ + u];
    __syncthreads();
    float acc = 0.f;
#pragma unroll 8
    for (int d = 0; d < D_; ++d)
        acc += qs[d] * W2[d * U_ + u];
    hidden[b * U_ + u] = acc;
}

// ---------------- Kernel 2: fused scores + chunk softmax + chunk context ----------
// Block: 128 t-rows x 256 u. 4 waves; wave w owns rows [w*32, w*32+32) x ALL u.
// W1^T hi/lo chunks [256u][32k] double-buffered in LDS via global_load_lds.
// A frag (lane l): value[t0+w*32+tf*16+(l&15)][k0+(l>>4)*8 + 0..7] (fp32->bf16 hi/lo)
// B frag (lane l): LDS[(uf*16+(l&15))*32 + (l>>4)*8 + 0..7]
// C (lane l, reg r): keys[w*32+tf*16+(l>>4)*4+r][uf*16+(l&15)]
__global__ __launch_bounds__(256, 2) void scores_ctx_kernel(
        const float* __restrict__ value,
        const unsigned short* __restrict__ w1t_hi,
        const unsigned short* __restrict__ w1t_lo,
        const float* __restrict__ Vv,
        const float* __restrict__ hidden,
        float* __restrict__ partial,
        float* __restrict__ mstat,
        float* __restrict__ lstat) {
    const int b    = blockIdx.y;
    const int bx   = blockIdx.x;
    const int t0   = bx * 128;
    const int tid  = threadIdx.x;
    const int w    = tid >> 6;
    const int lane = tid & 63;
    const int lr   = lane & 15;
    const int lk   = lane >> 4;

    __shared__ unsigned short bhi[2][256 * 32];
    __shared__ unsigned short blo[2][256 * 32];
    __shared__ float s_lds[128];
    __shared__ float e_lds[128];
    __shared__ float redm[4];
    __shared__ float redl[4];

    // stage W1T chunk [256u][32k] at k0 into LDS buffer bf (wave w stages rows w*64..w*64+64)
    const int srow = (lane >> 2);          // 0..15
    const int scol = (lane & 3) * 8;       // element offset 0,8,16,24
    auto stage_b = [&](int bf, int k0) {
#pragma unroll
        for (int i = 0; i < 4; ++i) {
            const unsigned short* g = w1t_hi + (size_t)(w * 64 + i * 16 + srow) * D_ + k0 + scol;
            __builtin_amdgcn_global_load_lds(
                (const __attribute__((address_space(1))) void*)g,
                (__attribute__((address_space(3))) void*)&bhi[bf][(w * 64 + i * 16) * 32],
                16, 0, 0);
        }
#pragma unroll
        for (int i = 0; i < 4; ++i) {
            const unsigned short* g = w1t_lo + (size_t)(w * 64 + i * 16 + srow) * D_ + k0 + scol;
            __builtin_amdgcn_global_load_lds(
                (const __attribute__((address_space(1))) void*)g,
                (__attribute__((address_space(3))) void*)&blo[bf][(w * 64 + i * 16) * 32],
                16, 0, 0);
        }
    };

    f32x4 acc[2][16] = {};
    const float* aptr = value + ((size_t)b * T_ + t0 + w * 32 + lr) * D_ + lk * 8;

    stage_b(0, 0);
    __syncthreads();

    int cur = 0;
    for (int k = 0; k < 8; ++k) {
        const int k0 = k << 5;
        if (k < 7) stage_b(cur ^ 1, k0 + 32);

        bf16x8 ah[2], al[2];
#pragma unroll
        for (int tf = 0; tf < 2; ++tf)
            cvt8(aptr + (size_t)tf * 16 * D_ + k0, ah[tf], al[tf]);

#pragma unroll
        for (int uf = 0; uf < 16; ++uf) {
            const bf16x8 bh = *reinterpret_cast<const bf16x8*>(&bhi[cur][(uf * 16 + lr) * 32 + lk * 8]);
            const bf16x8 bl = *reinterpret_cast<const bf16x8*>(&blo[cur][(uf * 16 + lr) * 32 + lk * 8]);
#pragma unroll
            for (int tf = 0; tf < 2; ++tf) {
                acc[tf][uf] = mfma16(ah[tf], bh, acc[tf][uf]);
                acc[tf][uf] = mfma16(al[tf], bh, acc[tf][uf]);
                acc[tf][uf] = mfma16(ah[tf], bl, acc[tf][uf]);
            }
        }
        __syncthreads();
        cur ^= 1;
    }

    // ---- epilogue: tanh + dot V, reduce over u within wave ----
    float hv[16], vwv[16];
#pragma unroll
    for (int uf = 0; uf < 16; ++uf) {
        const int u = uf * 16 + lr;
        hv[uf]  = hidden[b * U_ + u];
        vwv[uf] = Vv[u];
    }
#pragma unroll
    for (int tf = 0; tf < 2; ++tf) {
#pragma unroll
        for (int r = 0; r < 4; ++r) {
            float p = 0.f;
#pragma unroll
            for (int uf = 0; uf < 16; ++uf) {
                const float z = acc[tf][uf][r] + hv[uf];
                const float e = __expf(2.f * z);
                p += (1.f - __fdividef(2.f, e + 1.f)) * vwv[uf];
            }
            p += __shfl_xor(p, 1, 64);
            p += __shfl_xor(p, 2, 64);
            p += __shfl_xor(p, 4, 64);
            p += __shfl_xor(p, 8, 64);
            if (lr == 0) s_lds[w * 32 + tf * 16 + lk * 4 + r] = p;
        }
    }
    __syncthreads();

    // ---- chunk softmax (max, sum) over the 128 local scores ----
    float x = (tid < 128) ? s_lds[tid] : -3e38f;
#pragma unroll
    for (int m = 1; m < 64; m <<= 1) x = fmaxf(x, __shfl_xor(x, m, 64));
    if (lane == 0) redm[w] = x;
    __syncthreads();
    const float mc = fmaxf(fmaxf(redm[0], redm[1]), fmaxf(redm[2], redm[3]));

    float e = 0.f;
    if (tid < 128) {
        e = __expf(s_lds[tid] - mc);
        e_lds[tid] = e;
    }
    float l = e;
#pragma unroll
    for (int m = 1; m < 64; m <<= 1) l += __shfl_xor(l, m, 64);
    if (lane == 0) redl[w] = l;
    __syncthreads();
    const float lc = redl[0] + redl[1] + redl[2] + redl[3];

    // ---- chunk context: ctx[d] = sum_t e_t * value[t][d]  (rows are L1/L2-hot) ----
    const float* vb = value + ((size_t)b * T_ + t0) * D_ + tid;
    float a0 = 0.f, a1 = 0.f;
#pragma unroll 8
    for (int t = 0; t < 128; t += 2) {
        a0 += e_lds[t]     * vb[(size_t)t * D_];
        a1 += e_lds[t + 1] * vb[(size_t)(t + 1) * D_];
    }
    partial[((size_t)b * 64 + bx) * D_ + tid] = a0 + a1;
    if (tid == 0) {
        mstat[b * 64 + bx] = mc;
        lstat[b * 64 + bx] = lc;
    }
}

// ---------------- Kernel 3: cross-chunk softmax merge ----------------
__global__ __launch_bounds__(256) void combine_kernel(const float* __restrict__ partial,
                                                      const float* __restrict__ mstat,
                                                      const float* __restrict__ lstat,
                                                      float* __restrict__ out) {
    const int b = blockIdx.x;
    const int d = threadIdx.x;
    float M = -3e38f;
#pragma unroll 8
    for (int c = 0; c < 64; ++c) M = fmaxf(M, mstat[b * 64 + c]);
    float L = 0.f, a = 0.f;
#pragma unroll 4
    for (int c = 0; c < 64; ++c) {
        const float s = __expf(mstat[b * 64 + c] - M);
        L += lstat[b * 64 + c] * s;
        a += s * partial[((size_t)b * 64 + c) * D_ + d];
    }
    out[b * D_ + d] = a / L;
}

extern "C" void kernel_launch(void* const* d_in, const int* in_sizes, int n_in,
                              void* d_out, int out_size, void* d_ws, size_t ws_size,
                              hipStream_t stream) {
    const float* q     = (const float*)d_in[0];
    const float* value = (const float*)d_in[1];
    const float* W1    = (const float*)d_in[2];
    const float* W2    = (const float*)d_in[3];
    const float* Vv    = (const float*)d_in[4];
    float* out = (float*)d_out;

    char* ws = (char*)d_ws;
    unsigned short* w1t_hi  = (unsigned short*)(ws);                  // 131072 B
    unsigned short* w1t_lo  = (unsigned short*)(ws + 131072);         // 131072 B
    float*          hidden  = (float*)(ws + 262144);                  //  16384 B
    float*          partial = (float*)(ws + 278528);                  // 1048576 B (16*64*256*4)
    float*          mstat   = (float*)(ws + 1327104);                 //   4096 B
    float*          lstat   = (float*)(ws + 1331200);                 //   4096 B

    prep_w1t_kernel<<<dim3(256), dim3(256), 0, stream>>>(W1, w1t_hi, w1t_lo);
    hidden_kernel<<<dim3(B_), dim3(256), 0, stream>>>(q, W2, hidden);

    dim3 g2(T_ / 128, B_);
    scores_ctx_kernel<<<g2, dim3(256), 0, stream>>>(value, w1t_hi, w1t_lo, Vv, hidden,
                                                    partial, mstat, lstat);

    combine_kernel<<<dim3(B_), dim3(256), 0, stream>>>(partial, mstat, lstat, out);
}